// Round 3
// baseline (37.904 us; speedup 1.0000x reference)
//
#include <hip/hip_runtime.h>

#define BATCH   16
#define NANCH   25200
#define TPB     1024
#define MAXK    50
#define PRETOPK 2048
#define CONF_T  0.25f
#define IOU_T   0.45f
#define NEGV    -1000000000.0f
#define NBINS   4096
#define CHUNK   256   // candidates per round; single-wave in-register sortable

// bin over (0.25, 1.0+]: monotone in s, equal scores -> equal bins
__device__ __forceinline__ int bin_of(float s) {
    int b = (int)((s - CONF_T) * ((float)NBINS / 0.75f));
    return b > (NBINS - 1) ? (NBINS - 1) : b;
}

// K1: full-machine-parallel score extraction. Each thread covers 2 rows
// (3 coalesced float4 loads), writes 2 scores compact (float2, coalesced).
// Moves the strided 9.7MB HBM read off K2's 16-CU critical path.
__global__ __launch_bounds__(256) void score_extract(const float* __restrict__ x,
                                                     float* __restrict__ sc) {
    const int NPAIR = BATCH * NANCH / 2;  // 201600
    int t = blockIdx.x * 256 + threadIdx.x;
    if (t >= NPAIR) return;
    const float4* x4 = (const float4*)x;
    float4 v1 = x4[3 * (size_t)t + 1];    // scores at float 12t+4 -> f4[3t+1].x
    float4 v2 = x4[3 * (size_t)t + 2];    //           12t+10 -> f4[3t+2].z
    ((float2*)sc)[t] = make_float2(v1.x, v2.z);
}

// K2: one workgroup per batch image.
// Histogram-select top<=256 candidates -> in-register bitonic sort (exact
// (score desc, idx asc) order == lax.top_k tie semantics) -> serial greedy
// NMS on wave 0 with kept boxes one-per-lane. Multi-round over descending
// bin ranges keeps exact equivalence with the ref's top-2048 window.
template <bool FROM_WS>
__global__ __launch_bounds__(TPB, 1) void nms_kernel(const float* __restrict__ x,
                                                     const float* __restrict__ sc,
                                                     float* __restrict__ out) {
    __shared__ float s_scores[NANCH];                 // 100800 B
    __shared__ unsigned int s_hist[NBINS];            //  16384 B
    __shared__ unsigned long long s_keys[CHUNK];      //   2048 B
    __shared__ float s_rows[CHUNK][6];                //   6144 B
    __shared__ int s_hi, s_c, s_cnt, s_nk, s_P;

    const int b    = blockIdx.x;
    const int tid  = threadIdx.x;
    const int lane = tid & 63;
    const int wave = tid >> 6;

    const float* __restrict__ xb = x + (size_t)b * NANCH * 6;
    float* __restrict__ ob       = out + (size_t)b * MAXK * 6;

    for (int i = tid; i < NBINS; i += TPB) s_hist[i] = 0u;
    if (tid == 0) { s_hi = NBINS; s_nk = 0; s_P = 0; }
    __syncthreads();

    // Pass 1: stage thresholded scores + histogram.
    if (FROM_WS) {
        const float4* sb4 = (const float4*)(sc + (size_t)b * NANCH);
        for (int i = tid; i < NANCH / 4; i += TPB) {   // 6300 float4
            float4 v = sb4[i];
            const int base = i * 4;
            float ss[4] = {v.x, v.y, v.z, v.w};
            #pragma unroll
            for (int j = 0; j < 4; ++j) {
                bool valid = ss[j] > CONF_T;
                s_scores[base + j] = valid ? ss[j] : NEGV;
                if (valid) atomicAdd(&s_hist[bin_of(ss[j])], 1u);
            }
        }
    } else {
        for (int i = tid; i < NANCH; i += TPB) {
            float s = xb[(size_t)i * 6 + 4];
            bool valid = s > CONF_T;
            s_scores[i] = valid ? s : NEGV;
            if (valid) atomicAdd(&s_hist[bin_of(s)], 1u);
        }
    }
    __syncthreads();

    // Kept boxes live in wave-0 registers, one per lane (nk <= 50 < 64).
    float kx1 = 0.f, ky1 = 0.f, kx2 = 0.f, ky2 = 0.f, ka = 0.f;
    int nk = 0;

    while (s_nk < MAXK && s_P < PRETOPK && s_hi > 0) {
        // ---- wave 0: pick cutoff bin range [c, hi) with count <= CHUNK ----
        if (wave == 0) {
            int c = s_hi;
            int room = CHUNK;
            while (c > 0) {
                int nb = c < 64 ? c : 64;
                unsigned cnt = (lane < nb) ? s_hist[c - 1 - lane] : 0u;  // lane0 = highest bin
                unsigned pre = cnt;
                #pragma unroll
                for (int o = 1; o < 64; o <<= 1) {
                    unsigned t = __shfl_up(pre, o);
                    if (lane >= o) pre += t;
                }
                unsigned total = __shfl(pre, 63);
                if (total <= (unsigned)room) { room -= (int)total; c -= nb; continue; }
                unsigned long long m = __ballot((lane < nb) && (pre <= (unsigned)room));
                int n = __popcll(m);
                if (n == 0 && room == CHUNK) n = 1;  // >CHUNK ties in one bin (pathological)
                c -= n;
                break;
            }
            if (lane == 0) s_c = c;
        } else {
            int z = tid - 64;                    // waves 1..4 zero the staging arrays
            if (z < CHUNK) s_keys[z] = 0ULL;
            if (z == CHUNK) s_cnt = 0;
        }
        __syncthreads();

        const int c = s_c, hi = s_hi;

        // ---- collect candidates in [c, hi): key + full row into LDS ----
        for (int i = tid; i < NANCH; i += TPB) {
            float s = s_scores[i];
            if (s > CONF_T) {
                int bn = bin_of(s);
                if (bn >= c && bn < hi) {
                    int slot = atomicAdd(&s_cnt, 1);
                    if (slot < CHUNK) {
                        // key: [score_bits:32][inv_idx:15][slot:8]  (desc sort ->
                        // score desc, idx asc; pad key 0 sorts last)
                        unsigned long long key =
                            ((unsigned long long)__float_as_uint(s) << 23) |
                            ((unsigned long long)(32767 - i) << 8) |
                            (unsigned long long)slot;
                        s_keys[slot] = key;
                        const float2* rp = (const float2*)(xb + (size_t)i * 6);
                        float2 r0 = rp[0], r1 = rp[1], r2 = rp[2];
                        s_rows[slot][0] = r0.x; s_rows[slot][1] = r0.y;
                        s_rows[slot][2] = r1.x; s_rows[slot][3] = r1.y;
                        s_rows[slot][4] = r2.x; s_rows[slot][5] = r2.y;
                    }
                }
            }
        }
        __syncthreads();

        // ---- wave 0: in-register bitonic sort (256 = 64 lanes x 4 regs) + greedy ----
        if (wave == 0) {
            unsigned long long a[4];
            #pragma unroll
            for (int r = 0; r < 4; ++r) a[r] = s_keys[r * 64 + lane];

            // descending bitonic over virtual index v = r*64 + lane
            #pragma unroll
            for (int k = 2; k <= CHUNK; k <<= 1) {
                #pragma unroll
                for (int j = k >> 1; j > 0; j >>= 1) {
                    if (j >= 64) {
                        const int rj = j >> 6;
                        #pragma unroll
                        for (int r = 0; r < 4; ++r) {
                            if ((r & rj) == 0) {
                                const int rp = r | rj;
                                const int v = r * 64 + lane;
                                bool takeMax = ((v & k) == 0);
                                unsigned long long x0 = a[r], x1 = a[rp];
                                unsigned long long mx = x0 > x1 ? x0 : x1;
                                unsigned long long mn = x0 > x1 ? x1 : x0;
                                a[r]  = takeMax ? mx : mn;
                                a[rp] = takeMax ? mn : mx;
                            }
                        }
                    } else {
                        #pragma unroll
                        for (int r = 0; r < 4; ++r) {
                            const int v = r * 64 + lane;
                            unsigned long long other = __shfl_xor(a[r], j);
                            bool takeMax = (((v & k) == 0) != ((v & j) != 0));
                            unsigned long long mine = a[r];
                            bool gt = mine > other;
                            unsigned long long mx = gt ? mine : other;
                            unsigned long long mn = gt ? other : mine;
                            a[r] = takeMax ? mx : mn;
                        }
                    }
                }
            }

            int K    = s_cnt < CHUNK ? s_cnt : CHUNK;
            int rem  = PRETOPK - s_P;
            int Kproc = K < rem ? K : rem;

            for (int ii = 0; ii < Kproc && nk < MAXK; ++ii) {
                const int rr = ii >> 6;
                unsigned long long sel = rr == 0 ? a[0] : rr == 1 ? a[1] : rr == 2 ? a[2] : a[3];
                unsigned long long key = __shfl(sel, ii & 63);
                const int slot = (int)(key & 0xFFULL);
                const float bx1 = s_rows[slot][0], by1 = s_rows[slot][1];
                const float bx2 = s_rows[slot][2], by2 = s_rows[slot][3];
                const float ba  = fmaxf(bx2 - bx1, 0.0f) * fmaxf(by2 - by1, 0.0f);
                bool sup = false;
                if (lane < nk) {
                    float iw = fmaxf(fminf(bx2, kx2) - fmaxf(bx1, kx1), 0.0f);
                    float ih = fmaxf(fminf(by2, ky2) - fmaxf(by1, ky1), 0.0f);
                    float inter = iw * ih;
                    float uni   = ba + ka - inter;
                    sup = (inter / fmaxf(uni, 1e-9f)) >= IOU_T;
                }
                if (__ballot(sup) == 0ULL) {
                    if (lane == nk) {
                        kx1 = bx1; ky1 = by1; kx2 = bx2; ky2 = by2; ka = ba;
                        ob[nk * 6 + 0] = bx1;
                        ob[nk * 6 + 1] = by1;
                        ob[nk * 6 + 2] = bx2;
                        ob[nk * 6 + 3] = by2;
                        ob[nk * 6 + 4] = s_rows[slot][4];
                        ob[nk * 6 + 5] = s_rows[slot][5];
                    }
                    ++nk;
                }
            }
            if (lane == 0) { s_nk = nk; s_P = s_P + Kproc; s_hi = s_c; }
        }
        __syncthreads();
    }

    // Fill remaining rows with -1.0.
    const int nkf = s_nk;
    for (int i = tid; i < (MAXK - nkf) * 6; i += TPB) {
        ob[nkf * 6 + i] = -1.0f;
    }
}

extern "C" void kernel_launch(void* const* d_in, const int* in_sizes, int n_in,
                              void* d_out, int out_size, void* d_ws, size_t ws_size,
                              hipStream_t stream) {
    const float* x = (const float*)d_in[0];
    float* out     = (float*)d_out;
    const size_t need = (size_t)BATCH * NANCH * sizeof(float);  // 1.6 MB
    if (d_ws != nullptr && ws_size >= need) {
        float* sc = (float*)d_ws;
        const int npair = BATCH * NANCH / 2;
        score_extract<<<(npair + 255) / 256, 256, 0, stream>>>(x, sc);
        nms_kernel<true><<<BATCH, TPB, 0, stream>>>(x, sc, out);
    } else {
        // Fallback (tiny ws): validated R2 single-kernel path.
        nms_kernel<false><<<BATCH, TPB, 0, stream>>>(x, nullptr, out);
    }
}

// Round 4
// 31.385 us; speedup vs baseline: 1.2077x; 1.2077x over previous
//
#include <hip/hip_runtime.h>

#define BATCH   16
#define NANCH   25200
#define TPB     1024
#define MAXK    50
#define PRETOPK 2048
#define CONF_T  0.25f
#define IOU_T   0.45f
#define NEGV    -1000000000.0f
#define NBINS   4096
#define CHUNK   256   // candidates per round

// bin over (0.25, 1.0+]: monotone in s, equal scores -> equal bins
__device__ __forceinline__ int bin_of(float s) {
    int b = (int)((s - CONF_T) * ((float)NBINS / 0.75f));
    return b > (NBINS - 1) ? (NBINS - 1) : b;
}

// One workgroup per batch image.
// Histogram-select top<=256 candidates per round -> parallel counting-rank
// (exact (score desc, idx asc) == lax.top_k tie order) with rank-ordered row
// scatter -> software-pipelined serial greedy on wave 0 (kept boxes in lane
// registers). Multi-round over descending bin ranges == ref's top-2048 window.
__global__ __launch_bounds__(TPB, 1) void nms_kernel(const float* __restrict__ x,
                                                     float* __restrict__ out) {
    __shared__ float s_scores[NANCH];                 // 100800 B
    __shared__ unsigned int s_hist[NBINS];            //  16384 B
    __shared__ unsigned long long s_keys[CHUNK];      //   2048 B
    __shared__ float s_srows[CHUNK][8];               //   8192 B (stride 8: b128-aligned)
    __shared__ int s_hi, s_c, s_cnt, s_nk, s_P;

    const int b    = blockIdx.x;
    const int tid  = threadIdx.x;
    const int lane = tid & 63;
    const int wave = tid >> 6;

    const float* __restrict__ xb = x + (size_t)b * NANCH * 6;
    float* __restrict__ ob       = out + (size_t)b * MAXK * 6;

    for (int i = tid; i < NBINS; i += TPB) s_hist[i] = 0u;
    if (tid == 0) { s_hi = NBINS; s_nk = 0; s_P = 0; }
    __syncthreads();

    // Pass 1: stage thresholded scores + histogram.
    for (int i = tid; i < NANCH; i += TPB) {
        float s = xb[(size_t)i * 6 + 4];
        bool valid = s > CONF_T;
        s_scores[i] = valid ? s : NEGV;
        if (valid) atomicAdd(&s_hist[bin_of(s)], 1u);
    }
    __syncthreads();

    // Kept boxes live in wave-0 registers, one per lane (nk <= 50 < 64).
    float kx1 = 0.f, ky1 = 0.f, kx2 = 0.f, ky2 = 0.f, ka = 0.f;
    int nk = 0;

    while (s_nk < MAXK && s_P < PRETOPK && s_hi > 0) {
        // ---- wave 0: pick cutoff bin range [c, hi) with count <= CHUNK ----
        if (wave == 0) {
            int c = s_hi;
            int room = CHUNK;
            while (c > 0) {
                int nb = c < 64 ? c : 64;
                unsigned cnt = (lane < nb) ? s_hist[c - 1 - lane] : 0u;  // lane0 = highest bin
                unsigned pre = cnt;
                #pragma unroll
                for (int o = 1; o < 64; o <<= 1) {
                    unsigned t = __shfl_up(pre, o);
                    if (lane >= o) pre += t;
                }
                unsigned total = __shfl(pre, 63);
                if (total <= (unsigned)room) { room -= (int)total; c -= nb; continue; }
                unsigned long long m = __ballot((lane < nb) && (pre <= (unsigned)room));
                int n = __popcll(m);
                if (n == 0 && room == CHUNK) n = 1;  // >CHUNK ties in one bin (pathological)
                c -= n;
                break;
            }
            if (lane == 0) s_c = c;
        } else {
            int z = tid - 64;                    // waves 1..4 zero staging
            if (z < CHUNK) s_keys[z] = 0ULL;
            if (z == CHUNK) s_cnt = 0;
        }
        __syncthreads();

        const int c = s_c, hi = s_hi;

        // ---- collect candidate keys in [c, hi) ----
        for (int i = tid; i < NANCH; i += TPB) {
            float s = s_scores[i];
            if (s > CONF_T) {
                int bn = bin_of(s);
                if (bn >= c && bn < hi) {
                    int slot = atomicAdd(&s_cnt, 1);
                    if (slot < CHUNK) {
                        // key: [score_bits:32][65535-idx:16][slot:8+] -> u64 desc
                        // order == (score desc, idx asc); pad key 0 sorts last.
                        s_keys[slot] =
                            ((unsigned long long)__float_as_uint(s) << 32) |
                            ((unsigned long long)(65535 - i) << 16) |
                            (unsigned long long)slot;
                    }
                }
            }
        }
        __syncthreads();

        const int K = (s_cnt < CHUNK) ? s_cnt : CHUNK;

        // ---- parallel counting-rank + rank-ordered row scatter (threads 0..255) ----
        if (tid < CHUNK) {
            const unsigned long long mykey = s_keys[tid];
            // issue the row fetch early; L2 latency hides under the rank loop
            float2 r0, r1, r2;
            int myi = 0;
            const bool real = tid < K;
            if (real) {
                myi = 65535 - (int)((mykey >> 16) & 0xFFFFULL);
                const float2* rp = (const float2*)(xb + (size_t)myi * 6);
                r0 = rp[0]; r1 = rp[1]; r2 = rp[2];
            }
            int r = 0;
            #pragma unroll 4
            for (int j = 0; j < CHUNK; ++j) r += (s_keys[j] > mykey) ? 1 : 0;
            if (real) {
                s_srows[r][0] = r0.x; s_srows[r][1] = r0.y;
                s_srows[r][2] = r1.x; s_srows[r][3] = r1.y;
                s_srows[r][4] = r2.x; s_srows[r][5] = r2.y;
            }
        }
        __syncthreads();

        // ---- wave 0: software-pipelined serial greedy over sorted rows ----
        if (wave == 0) {
            const int rem   = PRETOPK - s_P;
            const int Kproc = K < rem ? K : rem;
            float4 nb0 = {0, 0, 0, 0}; float2 nb1 = {0, 0};
            if (Kproc > 0) {
                nb0 = *(const float4*)&s_srows[0][0];
                nb1 = *(const float2*)&s_srows[0][4];
            }
            for (int ii = 0; ii < Kproc && nk < MAXK; ++ii) {
                const float4 cb0 = nb0; const float2 cb1 = nb1;
                if (ii + 1 < Kproc) {   // prefetch next row while computing this one
                    nb0 = *(const float4*)&s_srows[ii + 1][0];
                    nb1 = *(const float2*)&s_srows[ii + 1][4];
                }
                const float ba = fmaxf(cb0.z - cb0.x, 0.0f) * fmaxf(cb0.w - cb0.y, 0.0f);
                bool sup = false;
                if (lane < nk) {
                    float iw = fmaxf(fminf(cb0.z, kx2) - fmaxf(cb0.x, kx1), 0.0f);
                    float ih = fmaxf(fminf(cb0.w, ky2) - fmaxf(cb0.y, ky1), 0.0f);
                    float inter = iw * ih;
                    float uni   = ba + ka - inter;
                    sup = (inter / fmaxf(uni, 1e-9f)) >= IOU_T;
                }
                if (__ballot(sup) == 0ULL) {
                    if (lane == nk) {
                        kx1 = cb0.x; ky1 = cb0.y; kx2 = cb0.z; ky2 = cb0.w; ka = ba;
                        ob[nk * 6 + 0] = cb0.x;
                        ob[nk * 6 + 1] = cb0.y;
                        ob[nk * 6 + 2] = cb0.z;
                        ob[nk * 6 + 3] = cb0.w;
                        ob[nk * 6 + 4] = cb1.x;
                        ob[nk * 6 + 5] = cb1.y;
                    }
                    ++nk;
                }
            }
            if (lane == 0) { s_nk = nk; s_P = s_P + Kproc; s_hi = s_c; }
        }
        __syncthreads();
    }

    // Fill remaining rows with -1.0.
    const int nkf = s_nk;
    for (int i = tid; i < (MAXK - nkf) * 6; i += TPB) {
        ob[nkf * 6 + i] = -1.0f;
    }
}

extern "C" void kernel_launch(void* const* d_in, const int* in_sizes, int n_in,
                              void* d_out, int out_size, void* d_ws, size_t ws_size,
                              hipStream_t stream) {
    const float* x = (const float*)d_in[0];
    float* out     = (float*)d_out;
    nms_kernel<<<BATCH, TPB, 0, stream>>>(x, out);
}

// Round 5
// 28.165 us; speedup vs baseline: 1.3458x; 1.1143x over previous
//
#include <hip/hip_runtime.h>

#define BATCH   16
#define NANCH   25200
#define TPB     1024
#define MAXK    50
#define PRETOPK 2048
#define CONF_T  0.25f
#define IOU_T   0.45f
#define NEGV    -1000000000.0f
#define NBINS   4096
#define CHUNK   256   // candidates per round

// bin over (0.25, 1.0+]: monotone in s, equal scores -> equal bins
__device__ __forceinline__ int bin_of(float s) {
    int b = (int)((s - CONF_T) * ((float)NBINS / 0.75f));
    return b > (NBINS - 1) ? (NBINS - 1) : b;
}

// One workgroup per batch image.
// Histogram-select top<=256 candidates per round -> parallel counting-rank
// (exact (score desc, idx asc) == lax.top_k tie order) -> 64-wide tile
// greedy on wave 0: pairwise IoU mask per lane (symmetric), sequential
// resolve with ballots only (~20cyc/keep), parallel output write.
// Multi-round over descending bin ranges == ref's top-2048 window.
__global__ __launch_bounds__(TPB, 1) void nms_kernel(const float* __restrict__ x,
                                                     float* __restrict__ out) {
    __shared__ float s_scores[NANCH];                 // 100800 B
    __shared__ unsigned int s_hist[NBINS];            //  16384 B
    __shared__ unsigned long long s_keys[CHUNK];      //   2048 B
    __shared__ float s_srows[CHUNK][8];               //   8192 B (stride 8: b128-aligned)
    __shared__ float s_kx1[MAXK], s_ky1[MAXK], s_kx2[MAXK], s_ky2[MAXK], s_ka[MAXK];
    __shared__ int s_hi, s_c, s_cnt, s_nk, s_P;

    const int b    = blockIdx.x;
    const int tid  = threadIdx.x;
    const int lane = tid & 63;
    const int wave = tid >> 6;

    const float* __restrict__ xb = x + (size_t)b * NANCH * 6;
    float* __restrict__ ob       = out + (size_t)b * MAXK * 6;

    for (int i = tid; i < NBINS; i += TPB) s_hist[i] = 0u;
    if (tid == 0) { s_hi = NBINS; s_nk = 0; s_P = 0; }
    __syncthreads();

    // Pass 1: stage thresholded scores + histogram.
    for (int i = tid; i < NANCH; i += TPB) {
        float s = xb[(size_t)i * 6 + 4];
        bool valid = s > CONF_T;
        s_scores[i] = valid ? s : NEGV;
        if (valid) atomicAdd(&s_hist[bin_of(s)], 1u);
    }
    __syncthreads();

    while (s_nk < MAXK && s_P < PRETOPK && s_hi > 0) {
        // ---- wave 0: pick cutoff bin range [c, hi) with count <= CHUNK ----
        if (wave == 0) {
            int c = s_hi;
            int room = CHUNK;
            while (c > 0) {
                int nb = c < 64 ? c : 64;
                unsigned cnt = (lane < nb) ? s_hist[c - 1 - lane] : 0u;  // lane0 = highest bin
                unsigned pre = cnt;
                #pragma unroll
                for (int o = 1; o < 64; o <<= 1) {
                    unsigned t = __shfl_up(pre, o);
                    if (lane >= o) pre += t;
                }
                unsigned total = __shfl(pre, 63);
                if (total <= (unsigned)room) { room -= (int)total; c -= nb; continue; }
                unsigned long long m = __ballot((lane < nb) && (pre <= (unsigned)room));
                int n = __popcll(m);
                if (n == 0 && room == CHUNK) n = 1;  // >CHUNK ties in one bin (pathological)
                c -= n;
                break;
            }
            if (lane == 0) s_c = c;
        } else {
            int z = tid - 64;                    // waves 1..4 zero staging
            if (z < CHUNK) s_keys[z] = 0ULL;
            if (z == CHUNK) s_cnt = 0;
        }
        __syncthreads();

        const int c = s_c, hi = s_hi;

        // ---- collect candidate keys in [c, hi) ----
        for (int i = tid; i < NANCH; i += TPB) {
            float s = s_scores[i];
            if (s > CONF_T) {
                int bn = bin_of(s);
                if (bn >= c && bn < hi) {
                    int slot = atomicAdd(&s_cnt, 1);
                    if (slot < CHUNK) {
                        // key: [score_bits:32][65535-idx:16][slot:16] -> u64 desc
                        // order == (score desc, idx asc); pad key 0 sorts last.
                        s_keys[slot] =
                            ((unsigned long long)__float_as_uint(s) << 32) |
                            ((unsigned long long)(65535 - i) << 16) |
                            (unsigned long long)slot;
                    }
                }
            }
        }
        __syncthreads();

        const int K = (s_cnt < CHUNK) ? s_cnt : CHUNK;

        // ---- parallel counting-rank + rank-ordered row scatter (threads 0..255) ----
        if (tid < CHUNK) {
            const unsigned long long mykey = s_keys[tid];
            // issue the row fetch early; L2 latency hides under the rank loop
            float2 r0, r1, r2;
            const bool real = tid < K;
            if (real) {
                int myi = 65535 - (int)((mykey >> 16) & 0xFFFFULL);
                const float2* rp = (const float2*)(xb + (size_t)myi * 6);
                r0 = rp[0]; r1 = rp[1]; r2 = rp[2];
            }
            int r = 0;
            #pragma unroll 4
            for (int j = 0; j < CHUNK; ++j) r += (s_keys[j] > mykey) ? 1 : 0;
            if (real) {
                s_srows[r][0] = r0.x; s_srows[r][1] = r0.y;
                s_srows[r][2] = r1.x; s_srows[r][3] = r1.y;
                s_srows[r][4] = r2.x; s_srows[r][5] = r2.y;
            }
        }
        __syncthreads();

        // ---- wave 0: 64-wide tile greedy over sorted rows ----
        if (wave == 0) {
            const int rem   = PRETOPK - s_P;
            const int Kproc = K < rem ? K : rem;
            int nk = s_nk;

            for (int tb = 0; tb < Kproc && nk < MAXK; tb += 64) {
                const int lim = (Kproc - tb) < 64 ? (Kproc - tb) : 64;
                float4 bx = {0.f, 0.f, 0.f, 0.f};
                float2 be = {0.f, 0.f};
                bool sup = lane >= lim;
                if (!sup) {
                    bx = *(const float4*)&s_srows[tb + lane][0];
                    be = *(const float2*)&s_srows[tb + lane][4];
                }
                const float ba = fmaxf(bx.z - bx.x, 0.f) * fmaxf(bx.w - bx.y, 0.f);

                // (A) vs previously-kept boxes (LDS broadcast; empty on 1st tile)
                for (int j = 0; j < nk; ++j) {
                    float iw = fmaxf(fminf(bx.z, s_kx2[j]) - fmaxf(bx.x, s_kx1[j]), 0.f);
                    float ih = fmaxf(fminf(bx.w, s_ky2[j]) - fmaxf(bx.y, s_ky1[j]), 0.f);
                    float inter = iw * ih;
                    sup = sup || (inter / fmaxf(ba + s_ka[j] - inter, 1e-9f)) >= IOU_T;
                }

                // (B) pairwise overlap mask within tile (symmetric; pure VALU)
                unsigned long long m = 0ULL;
                #pragma unroll 8
                for (int j = 0; j < 64; ++j) {
                    if (j >= lim) break;
                    const float4 oj = *(const float4*)&s_srows[tb + j][0];  // broadcast
                    const float oa = fmaxf(oj.z - oj.x, 0.f) * fmaxf(oj.w - oj.y, 0.f);
                    float iw = fmaxf(fminf(bx.z, oj.z) - fmaxf(bx.x, oj.x), 0.f);
                    float ih = fmaxf(fminf(bx.w, oj.w) - fmaxf(bx.y, oj.y), 0.f);
                    float inter = iw * ih;
                    bool ov = (inter / fmaxf(ba + oa - inter, 1e-9f)) >= IOU_T;
                    m |= ov ? (1ULL << j) : 0ULL;
                }
                m &= ~(1ULL << lane);   // no self-suppression

                // (C) sequential resolve: keep lowest alive, kill its overlaps
                unsigned long long alive = __ballot(!sup);
                unsigned long long keepmask = 0ULL;
                while (alive != 0ULL && nk < MAXK) {
                    const int j = __builtin_ctzll(alive);
                    keepmask |= 1ULL << j;
                    ++nk;
                    const unsigned long long kill = __ballot((m >> j) & 1ULL);
                    alive &= ~(kill | (1ULL << j));
                }

                // (D) parallel write of kept rows (exact greedy order)
                if ((keepmask >> lane) & 1ULL) {
                    const int nk0 = nk - __popcll(keepmask);
                    const int pos = nk0 + __popcll(keepmask & ((1ULL << lane) - 1ULL));
                    s_kx1[pos] = bx.x; s_ky1[pos] = bx.y;
                    s_kx2[pos] = bx.z; s_ky2[pos] = bx.w; s_ka[pos] = ba;
                    ob[pos * 6 + 0] = bx.x;
                    ob[pos * 6 + 1] = bx.y;
                    ob[pos * 6 + 2] = bx.z;
                    ob[pos * 6 + 3] = bx.w;
                    ob[pos * 6 + 4] = be.x;
                    ob[pos * 6 + 5] = be.y;
                }
            }
            if (lane == 0) { s_nk = nk; s_P = s_P + Kproc; s_hi = s_c; }
        }
        __syncthreads();
    }

    // Fill remaining rows with -1.0.
    const int nkf = s_nk;
    for (int i = tid; i < (MAXK - nkf) * 6; i += TPB) {
        ob[nkf * 6 + i] = -1.0f;
    }
}

extern "C" void kernel_launch(void* const* d_in, const int* in_sizes, int n_in,
                              void* d_out, int out_size, void* d_ws, size_t ws_size,
                              hipStream_t stream) {
    const float* x = (const float*)d_in[0];
    float* out     = (float*)d_out;
    nms_kernel<<<BATCH, TPB, 0, stream>>>(x, out);
}

// Round 6
// 25.539 us; speedup vs baseline: 1.4842x; 1.1028x over previous
//
#include <hip/hip_runtime.h>

#define BATCH   16
#define NANCH   25200
#define TPB     1024
#define NWAVES  (TPB / 64)
#define MAXK    50
#define PRETOPK 2048
#define CONF_T  0.25f
#define IOU_T   0.45f
#define NEGV    -1000000000.0f
#define T0      0.9905f   // fixed collect threshold: E[cnt]=239, P(cnt>CAP)~8e-8
#define CAP     320       // candidate capacity (5 waves for rank)

// One workgroup per batch image.
// Fast path (always taken on this data): single fused pass stages scores to
// LDS and collects all s > T0 (~240) -> counting-rank (exact (score desc,
// idx asc) == lax.top_k tie order) -> 64-wide tile greedy (R5-validated).
// Fallback (exact, never taken here): R1-validated iterative argmax greedy
// with 2048-pop budget over the LDS score array.
__global__ __launch_bounds__(TPB, 1) void nms_kernel(const float* __restrict__ x,
                                                     float* __restrict__ out) {
    __shared__ float s_scores[NANCH];                 // 100800 B
    __shared__ unsigned long long s_keys[CAP];        //   2560 B
    __shared__ float s_srows[CAP][8];                 //  10240 B (b128-aligned rows)
    __shared__ float s_kx1[MAXK], s_ky1[MAXK], s_kx2[MAXK], s_ky2[MAXK], s_ka[MAXK];
    __shared__ float s_wval[NWAVES];
    __shared__ int   s_widx[NWAVES];
    __shared__ int   s_cnt, s_nk, s_best;

    const int b    = blockIdx.x;
    const int tid  = threadIdx.x;
    const int lane = tid & 63;
    const int wave = tid >> 6;

    const float* __restrict__ xb = x + (size_t)b * NANCH * 6;
    float* __restrict__ ob       = out + (size_t)b * MAXK * 6;

    if (tid < CAP) s_keys[tid] = 0ULL;
    if (tid == 0) { s_cnt = 0; s_nk = 0; }
    __syncthreads();

    // ---- fused pass: stage scores + collect s > T0 (unroll 8 for MLP) ----
    {
        int i = tid;
        for (int c = 0; c < 3; ++c) {                  // 3*8*1024 = 24576
            float v[8];
            #pragma unroll
            for (int k = 0; k < 8; ++k) v[k] = xb[(size_t)(i + k * TPB) * 6 + 4];
            #pragma unroll
            for (int k = 0; k < 8; ++k) {
                const int idx = i + k * TPB;
                s_scores[idx] = (v[k] > CONF_T) ? v[k] : NEGV;
                if (v[k] > T0) {
                    int slot = atomicAdd(&s_cnt, 1);
                    if (slot < CAP)
                        s_keys[slot] =
                            ((unsigned long long)__float_as_uint(v[k]) << 32) |
                            ((unsigned long long)(65535 - idx) << 16) |
                            (unsigned long long)slot;
                }
            }
            i += 8 * TPB;
        }
        if (i < NANCH) {                               // tail 624 anchors
            float s = xb[(size_t)i * 6 + 4];
            s_scores[i] = (s > CONF_T) ? s : NEGV;
            if (s > T0) {
                int slot = atomicAdd(&s_cnt, 1);
                if (slot < CAP)
                    s_keys[slot] =
                        ((unsigned long long)__float_as_uint(s) << 32) |
                        ((unsigned long long)(65535 - i) << 16) |
                        (unsigned long long)slot;
            }
        }
    }
    __syncthreads();

    const int cnt   = s_cnt;
    const bool fast = cnt <= CAP;

    if (fast) {
        // ---- counting-rank + rank-ordered row scatter (threads 0..319) ----
        if (tid < CAP) {
            const unsigned long long mykey = s_keys[tid];
            float2 r0, r1, r2;
            const bool real = tid < cnt;
            if (real) {   // issue row fetch early; hides under rank loop (L1/L2-hot)
                int myi = 65535 - (int)((mykey >> 16) & 0xFFFFULL);
                const float2* rp = (const float2*)(xb + (size_t)myi * 6);
                r0 = rp[0]; r1 = rp[1]; r2 = rp[2];
            }
            int r = 0;
            #pragma unroll 4
            for (int j = 0; j < CAP; ++j) r += (s_keys[j] > mykey) ? 1 : 0;
            if (real) {
                s_srows[r][0] = r0.x; s_srows[r][1] = r0.y;
                s_srows[r][2] = r1.x; s_srows[r][3] = r1.y;
                s_srows[r][4] = r2.x; s_srows[r][5] = r2.y;
            }
        }
        __syncthreads();

        // ---- wave 0: 64-wide tile greedy over sorted rows (R5-validated) ----
        if (wave == 0) {
            int nk = 0;
            for (int tb = 0; tb < cnt && nk < MAXK; tb += 64) {
                const int lim = (cnt - tb) < 64 ? (cnt - tb) : 64;
                float4 bx = {0.f, 0.f, 0.f, 0.f};
                float2 be = {0.f, 0.f};
                bool sup = lane >= lim;
                if (!sup) {
                    bx = *(const float4*)&s_srows[tb + lane][0];
                    be = *(const float2*)&s_srows[tb + lane][4];
                }
                const float ba = fmaxf(bx.z - bx.x, 0.f) * fmaxf(bx.w - bx.y, 0.f);

                // (A) vs previously-kept boxes (empty on 1st tile)
                for (int j = 0; j < nk; ++j) {
                    float iw = fmaxf(fminf(bx.z, s_kx2[j]) - fmaxf(bx.x, s_kx1[j]), 0.f);
                    float ih = fmaxf(fminf(bx.w, s_ky2[j]) - fmaxf(bx.y, s_ky1[j]), 0.f);
                    float inter = iw * ih;
                    sup = sup || (inter / fmaxf(ba + s_ka[j] - inter, 1e-9f)) >= IOU_T;
                }

                // (B) pairwise overlap mask within tile (symmetric; pure VALU)
                unsigned long long m = 0ULL;
                #pragma unroll 8
                for (int j = 0; j < 64; ++j) {
                    if (j >= lim) break;
                    const float4 oj = *(const float4*)&s_srows[tb + j][0];  // broadcast
                    const float oa = fmaxf(oj.z - oj.x, 0.f) * fmaxf(oj.w - oj.y, 0.f);
                    float iw = fmaxf(fminf(bx.z, oj.z) - fmaxf(bx.x, oj.x), 0.f);
                    float ih = fmaxf(fminf(bx.w, oj.w) - fmaxf(bx.y, oj.y), 0.f);
                    float inter = iw * ih;
                    bool ov = (inter / fmaxf(ba + oa - inter, 1e-9f)) >= IOU_T;
                    m |= ov ? (1ULL << j) : 0ULL;
                }
                m &= ~(1ULL << lane);

                // (C) sequential resolve with cheap ops only
                unsigned long long alive = __ballot(!sup);
                unsigned long long keepmask = 0ULL;
                while (alive != 0ULL && nk < MAXK) {
                    const int j = __builtin_ctzll(alive);
                    keepmask |= 1ULL << j;
                    ++nk;
                    const unsigned long long kill = __ballot((m >> j) & 1ULL);
                    alive &= ~(kill | (1ULL << j));
                }

                // (D) parallel write of kept rows (exact greedy order)
                if ((keepmask >> lane) & 1ULL) {
                    const int nk0 = nk - __popcll(keepmask);
                    const int pos = nk0 + __popcll(keepmask & ((1ULL << lane) - 1ULL));
                    s_kx1[pos] = bx.x; s_ky1[pos] = bx.y;
                    s_kx2[pos] = bx.z; s_ky2[pos] = bx.w; s_ka[pos] = ba;
                    ob[pos * 6 + 0] = bx.x;
                    ob[pos * 6 + 1] = bx.y;
                    ob[pos * 6 + 2] = bx.z;
                    ob[pos * 6 + 3] = bx.w;
                    ob[pos * 6 + 4] = be.x;
                    ob[pos * 6 + 5] = be.y;
                }
            }
            if (lane == 0) s_nk = nk;
        }
        __syncthreads();
    }

    // ---- fallback / continuation (exact; never taken on this data) ----
    const bool cont = fast && (s_nk < MAXK);
    if (cont) {   // sentinel the already-processed (> T0) scores
        for (int i = tid; i < NANCH; i += TPB)
            if (s_scores[i] > T0) s_scores[i] = NEGV;
    }
    __syncthreads();

    int budget = 0;
    if (!fast)     budget = PRETOPK;
    else if (cont) budget = PRETOPK - cnt;

    if (budget > 0) {
        int nk = s_nk;
        for (int pop = 0; pop < budget && nk < MAXK; ++pop) {
            // two-level argmax (score desc, index asc) — R1-validated
            float bv = NEGV - 1.0f;
            int   bi = NANCH;
            for (int i = tid; i < NANCH; i += TPB) {
                float s = s_scores[i];
                if (s > bv) { bv = s; bi = i; }
            }
            #pragma unroll
            for (int off = 32; off >= 1; off >>= 1) {
                float ov = __shfl_down(bv, off);
                int   oi = __shfl_down(bi, off);
                if (ov > bv || (ov == bv && oi < bi)) { bv = ov; bi = oi; }
            }
            if (lane == 0) { s_wval[wave] = bv; s_widx[wave] = bi; }
            __syncthreads();
            if (wave == 0) {
                bv = (lane < NWAVES) ? s_wval[lane] : (NEGV - 1.0f);
                bi = (lane < NWAVES) ? s_widx[lane] : NANCH;
                #pragma unroll
                for (int off = 32; off >= 1; off >>= 1) {
                    float ov = __shfl_down(bv, off);
                    int   oi = __shfl_down(bi, off);
                    if (ov > bv || (ov == bv && oi < bi)) { bv = ov; bi = oi; }
                }
                if (lane == 0) {
                    s_best = (bv > 0.5f * NEGV) ? bi : -1;
                    if (s_best >= 0) s_scores[bi] = NEGV - 1.0f;
                }
            }
            __syncthreads();
            const int best = s_best;
            if (best < 0) break;

            if (wave == 0) {
                const float bx1 = xb[(size_t)best * 6 + 0];
                const float by1 = xb[(size_t)best * 6 + 1];
                const float bx2 = xb[(size_t)best * 6 + 2];
                const float by2 = xb[(size_t)best * 6 + 3];
                const float ba  = fmaxf(bx2 - bx1, 0.0f) * fmaxf(by2 - by1, 0.0f);
                bool sup = false;
                if (lane < nk) {
                    float iw = fmaxf(fminf(bx2, s_kx2[lane]) - fmaxf(bx1, s_kx1[lane]), 0.f);
                    float ih = fmaxf(fminf(by2, s_ky2[lane]) - fmaxf(by1, s_ky1[lane]), 0.f);
                    float inter = iw * ih;
                    float uni   = ba + s_ka[lane] - inter;
                    sup = (inter / fmaxf(uni, 1e-9f)) >= IOU_T;
                }
                if (lane == 0 && __ballot(sup) == 0ULL) {
                    s_kx1[nk] = bx1; s_ky1[nk] = by1;
                    s_kx2[nk] = bx2; s_ky2[nk] = by2; s_ka[nk] = ba;
                    ob[nk * 6 + 0] = bx1;
                    ob[nk * 6 + 1] = by1;
                    ob[nk * 6 + 2] = bx2;
                    ob[nk * 6 + 3] = by2;
                    ob[nk * 6 + 4] = xb[(size_t)best * 6 + 4];
                    ob[nk * 6 + 5] = xb[(size_t)best * 6 + 5];
                    s_nk = nk + 1;
                }
            }
            __syncthreads();
            nk = s_nk;
        }
    }
    __syncthreads();

    // Fill remaining rows with -1.0.
    const int nkf = s_nk;
    for (int i = tid; i < (MAXK - nkf) * 6; i += TPB) {
        ob[nkf * 6 + i] = -1.0f;
    }
}

extern "C" void kernel_launch(void* const* d_in, const int* in_sizes, int n_in,
                              void* d_out, int out_size, void* d_ws, size_t ws_size,
                              hipStream_t stream) {
    const float* x = (const float*)d_in[0];
    float* out     = (float*)d_out;
    nms_kernel<<<BATCH, TPB, 0, stream>>>(x, out);
}